// Round 5
// baseline (328.508 us; speedup 1.0000x reference)
//
#include <hip/hip_runtime.h>

// Truncated signature, depth=3, C=8, B=512, L=8192.
// Kernel 1: one wave per (sample, chunk); sequential Chen steps over the chunk.
//   lane (a,b)=(lane>>3, lane&7) owns S2[a][b], S3[a][b][0..7].
//   Level-3 via Abel summation:
//     S3[k] = sum_v (cf_{v-1}-cf_v) * p[k][v]  + cf_last * p[k][te]
//   where cf is the true level-2 coefficient (cf = S2 + S1*db/2 + da*db/6).
//   p[k][v] is wave-uniform raw path data -> scalar (SMEM) loads, no LDS traffic.
//   LDS holds ONLY dx/2 in [c][t] layout (stride 68) for per-lane da/db b128 reads.
//   S3 accumulated as even/odd float2 partials via packed fp32 fma.
// Kernel 2: per-sample in-order Chen combine of the G chunk signatures.

typedef float f2 __attribute__((ext_vector_type(2)));

constexpr int B_ = 512;
constexpr int C_ = 8;
constexpr int L_ = 8192;
constexpr int NINC = L_ - 1;      // 8191 increments
constexpr int SIGDIM = 584;       // 8 + 64 + 512
constexpr int TILE = 64;          // steps per LDS tile
constexpr int BSTR = 68;          // dx row stride (floats): 68%32=4 spreads rows
constexpr int BWSZ = C_ * BSTR;   // 544 floats/wave

// Recurrence on halved increments (DA=da/2, DB=db/2), true-scale outputs:
//   CFV = S2 + db/2*S1 + da*db/6 ; S2 += db*S1 + da*db/2 ; s1a += da
#define RSTEP(DA, DB, CFV)                                    \
  do {                                                        \
    const float w_ = __builtin_fmaf((DA), (2.f/3.f), s1a);    \
    const float z_ = __builtin_fmaf((DA), (4.f/3.f), s1a);    \
    (CFV) = __builtin_fmaf((DB), w_, S2);                     \
    S2  = __builtin_fmaf((DB), z_, (CFV));                    \
    s1a = __builtin_fmaf((DA), 2.f, s1a);                     \
  } while (0)

__global__ __launch_bounds__(256, 4)
void sig_chunks_kernel(const float* __restrict__ path, float* __restrict__ csig,
                       int G, int CPC) {
  __shared__ __align__(16) float Bs[4][BWSZ];
  const int wid  = __builtin_amdgcn_readfirstlane((int)(threadIdx.x >> 6));
  const int lane = (int)(threadIdx.x & 63);
  const int ia = lane >> 3;   // 'a' == staging channel
  const int ib = lane & 7;    // 'b' == staging position
  const int wglob = __builtin_amdgcn_readfirstlane((int)blockIdx.x) * 4 + wid;
  const int samp = wglob / G;
  const int g    = wglob - samp * G;
  const int ts = g * CPC;
  const int te = (ts + CPC < NINC) ? (ts + CPC) : NINC;   // exclusive end
  const float* pbase = path + (size_t)samp * (C_ * L_);   // uniform
  float* bs = Bs[wid];

  const int si = ib;
  const float* prow = pbase + ia * L_;     // per-lane staging row
  const int grp = lane & ~7;
  const float* pa = bs + ia * BSTR;
  const float* pb = bs + ib * BSTR;

  f2 S3p[8];
#pragma unroll
  for (int k = 0; k < 8; ++k) S3p[k] = f2{0.f, 0.f};
  float S2 = 0.f, s1a = 0.f, cfp = 0.f;

  const int ntiles = (CPC + TILE - 1) / TILE;   // uniform across grid

  // prologue: prefetch tile 0 + boundary
  float4 r0 = *(const float4*)(prow + ts + si * 4);
  float4 r1 = *(const float4*)(prow + ts + 32 + si * 4);
  float bnd = prow[ts + TILE];

  for (int tt = 0; tt < ntiles; ++tt) {
    const int t0 = ts + tt * TILE;
    const int cnt_ = te - t0;
    const int cnt = (cnt_ < TILE) ? cnt_ : TILE;

    // ---- stage tile tt: halved diffs into [c][t] LDS ----
    {
      const float4 v0 = r0, v1 = r1;
      const float sA = __shfl(v0.x, lane + 1);
      const float sB = __shfl(v1.x, grp);
      const float sC = __shfl(v1.x, lane + 1);
      const float n0 = (si == 7) ? sB : sA;
      const float n1 = (si == 7) ? bnd : sC;
      float4 d0, d1;
      d0.x = (v0.y - v0.x) * 0.5f;
      d0.y = (v0.z - v0.y) * 0.5f;
      d0.z = (v0.w - v0.z) * 0.5f;
      d0.w = (n0 - v0.w) * 0.5f;
      d1.x = (v1.y - v1.x) * 0.5f;
      d1.y = (v1.z - v1.y) * 0.5f;
      d1.z = (v1.w - v1.z) * 0.5f;
      d1.w = (n1 - v1.w) * 0.5f;
      *(float4*)(bs + ia * BSTR + si * 4) = d0;
      *(float4*)(bs + ia * BSTR + 32 + si * 4) = d1;
    }

    // ---- prefetch tile tt+1 ----
    if (tt + 1 < ntiles) {
      const int t1g = t0 + TILE;
      r0 = *(const float4*)(prow + t1g + si * 4);
      r1 = *(const float4*)(prow + t1g + 32 + si * 4);
      const int bn = t1g + TILE;
      bnd = (bn < L_) ? prow[bn] : 0.f;
    }

    // ---- compute tile tt in 8-step blocks ----
    if (cnt == TILE) {
#pragma unroll
      for (int blk = 0; blk < 8; ++blk) {
        const int u0 = blk * 8;
        const float4 a0 = *(const float4*)(pa + u0);
        const float4 a1 = *(const float4*)(pa + u0 + 4);
        const float4 b0 = *(const float4*)(pb + u0);
        const float4 b1 = *(const float4*)(pb + u0 + 4);
        float c0, c1, c2, c3, c4, c5, c6, c7;
        RSTEP(a0.x, b0.x, c0);
        RSTEP(a0.y, b0.y, c1);
        RSTEP(a0.z, b0.z, c2);
        RSTEP(a0.w, b0.w, c3);
        RSTEP(a1.x, b1.x, c4);
        RSTEP(a1.y, b1.y, c5);
        RSTEP(a1.z, b1.z, c6);
        RSTEP(a1.w, b1.w, c7);
        f2 dp0, dp1, dp2, dp3;
        dp0.x = cfp - c0; dp0.y = c0 - c1;
        dp1.x = c1 - c2;  dp1.y = c2 - c3;
        dp2.x = c3 - c4;  dp2.y = c4 - c5;
        dp3.x = c5 - c6;  dp3.y = c6 - c7;
        cfp = c7;
        const float* ps = pbase + t0 + u0;     // uniform base
#pragma unroll
        for (int k = 0; k < 8; ++k) {
          const float4 q0 = *(const float4*)(ps + k * L_);       // uniform -> SMEM
          const float4 q1 = *(const float4*)(ps + k * L_ + 4);   // uniform -> SMEM
          const f2 pA = {q0.x, q0.y};
          const f2 pB = {q0.z, q0.w};
          const f2 pC = {q1.x, q1.y};
          const f2 pD = {q1.z, q1.w};
          S3p[k] = __builtin_elementwise_fma(dp0, pA, S3p[k]);
          S3p[k] = __builtin_elementwise_fma(dp1, pB, S3p[k]);
          S3p[k] = __builtin_elementwise_fma(dp2, pC, S3p[k]);
          S3p[k] = __builtin_elementwise_fma(dp3, pD, S3p[k]);
        }
      }
    } else {
      // tail tile (only last chunk's last tile, cnt=63): cold path.
      // All p reads stay in-bounds (v <= te <= 8191); pad with d=0.
      for (int blk = 0; blk < 8; ++blk) {
        const int u0 = blk * 8;
        int m = cnt - u0; if (m > 8) m = 8;
        if (m <= 0) break;
        const float4 a0 = *(const float4*)(pa + u0);
        const float4 a1 = *(const float4*)(pa + u0 + 4);
        const float4 b0 = *(const float4*)(pb + u0);
        const float4 b1 = *(const float4*)(pb + u0 + 4);
        const float da[8] = {a0.x, a0.y, a0.z, a0.w, a1.x, a1.y, a1.z, a1.w};
        const float db[8] = {b0.x, b0.y, b0.z, b0.w, b1.x, b1.y, b1.z, b1.w};
        float d[8];
#pragma unroll
        for (int u = 0; u < 8; ++u) {
          if (u < m) {
            float cf;
            RSTEP(da[u], db[u], cf);
            d[u] = cfp - cf;
            cfp = cf;
          } else {
            d[u] = 0.f;
          }
        }
        const f2 dp0 = {d[0], d[1]}, dp1 = {d[2], d[3]};
        const f2 dp2 = {d[4], d[5]}, dp3 = {d[6], d[7]};
        const float* ps = pbase + t0 + u0;
#pragma unroll
        for (int k = 0; k < 8; ++k) {
          const float4 q0 = *(const float4*)(ps + k * L_);
          const float4 q1 = *(const float4*)(ps + k * L_ + 4);
          const f2 pA = {q0.x, q0.y};
          const f2 pB = {q0.z, q0.w};
          const f2 pC = {q1.x, q1.y};
          const f2 pD = {q1.z, q1.w};
          S3p[k] = __builtin_elementwise_fma(dp0, pA, S3p[k]);
          S3p[k] = __builtin_elementwise_fma(dp1, pB, S3p[k]);
          S3p[k] = __builtin_elementwise_fma(dp2, pC, S3p[k]);
          S3p[k] = __builtin_elementwise_fma(dp3, pD, S3p[k]);
        }
      }
    }
  }

  // Abel boundary + fold partials: S3[k] = S3e + S3o + cfp * p[k][te]
  float S3f[8];
  const float* pe = pbase + te;   // uniform
#pragma unroll
  for (int k = 0; k < 8; ++k)
    S3f[k] = S3p[k].x + S3p[k].y + cfp * pe[k * L_];

  float* cs = csig + ((size_t)samp * G + g) * SIGDIM;
  if (ib == 0) cs[ia] = s1a;
  cs[8 + lane] = S2;
  float4 o0, o1;
  o0.x = S3f[0]; o0.y = S3f[1]; o0.z = S3f[2]; o0.w = S3f[3];
  o1.x = S3f[4]; o1.y = S3f[5]; o1.z = S3f[6]; o1.w = S3f[7];
  *(float4*)(cs + 72 + lane * 8)     = o0;
  *(float4*)(cs + 72 + lane * 8 + 4) = o1;
}

__global__ __launch_bounds__(256)
void sig_combine_kernel(const float* __restrict__ csig, float* __restrict__ out, int G) {
  const int wid  = __builtin_amdgcn_readfirstlane((int)(threadIdx.x >> 6));
  const int lane = (int)(threadIdx.x & 63);
  const int ia = lane >> 3, ib = lane & 7;
  const int samp = __builtin_amdgcn_readfirstlane((int)blockIdx.x) * 4 + wid;
  const float* base = csig + (size_t)samp * G * SIGDIM;

  float R1a = base[ia];
  float R2  = base[8 + lane];
  float R3[8];
#pragma unroll
  for (int k = 0; k < 8; ++k) R3[k] = base[72 + lane * 8 + k];

  for (int g = 1; g < G; ++g) {
    const float* T = base + g * SIGDIM;
    float sT1[8];
#pragma unroll
    for (int k = 0; k < 8; ++k) sT1[k] = T[k];
    const float T1a  = T[ia];
    const float T1b  = T[ib];
    const float T2ab = T[8 + lane];
    float T2b[8], T3v[8];
#pragma unroll
    for (int k = 0; k < 8; ++k) T2b[k] = T[8 + ib * 8 + k];
#pragma unroll
    for (int k = 0; k < 8; ++k) T3v[k] = T[72 + lane * 8 + k];
    const float R1o = R1a, R2o = R2;
#pragma unroll
    for (int k = 0; k < 8; ++k)
      R3[k] += T3v[k] + R1o * T2b[k] + R2o * sT1[k];
    R2  += T2ab + R1o * T1b;
    R1a += T1a;
  }

  float* o = out + (size_t)samp * SIGDIM;
  if (ib == 0) o[ia] = R1a;
  o[8 + lane] = R2;
#pragma unroll
  for (int k = 0; k < 8; ++k) o[72 + lane * 8 + k] = R3[k];
}

extern "C" void kernel_launch(void* const* d_in, const int* in_sizes, int n_in,
                              void* d_out, int out_size, void* d_ws, size_t ws_size,
                              hipStream_t stream) {
  (void)in_sizes; (void)n_in; (void)out_size;
  const float* path = (const float*)d_in[0];
  float* out = (float*)d_out;
  float* ws  = (float*)d_ws;

  int G = 16;
  while (G > 1 && (size_t)B_ * G * SIGDIM * sizeof(float) > ws_size) G >>= 1;
  const int CPC = (NINC + G - 1) / G;   // increments per chunk

  sig_chunks_kernel<<<dim3(B_ * G / 4), dim3(256), 0, stream>>>(path, ws, G, CPC);
  sig_combine_kernel<<<dim3(B_ / 4), dim3(256), 0, stream>>>(ws, out, G);
}

// Round 7
// 244.790 us; speedup vs baseline: 1.3420x; 1.3420x over previous
//
#include <hip/hip_runtime.h>

// Truncated signature, depth=3, C=8, B=512, L=8192.
// Kernel 1: one wave per (sample, chunk); sequential Chen steps over the chunk.
//   lane (a,b)=(lane>>3, lane&7) owns S2[a][b], S3[a][b][0..7].
//   Level-3 via Abel summation over the chunk:
//     S3[k] = sum_v (cf_{v-1}-cf_v) * p[k][v] + cf_last * p[k][te],  cf_{ts-1}=0
//   cf = true level-2 coefficient (S2 + S1*db/2 + da*db/6).
//   p[k][v] is wave-uniform -> global_load float4 with identical address in all
//   lanes (1 coalesced line request, L1/L2-hot from staging). Zero DS traffic.
//   LDS holds ONLY dx/2 in [c][t] layout (stride 68), per-wave private, no
//   barriers; per-lane da/db come from 4x ds_read_b128 per 8-step block.
// Kernel 2: per-sample in-order Chen combine of the G chunk signatures.

constexpr int B_ = 512;
constexpr int C_ = 8;
constexpr int L_ = 8192;
constexpr int NINC = L_ - 1;      // 8191 increments
constexpr int SIGDIM = 584;       // 8 + 64 + 512
constexpr int TILE = 64;          // steps per LDS tile
constexpr int BSTR = 68;          // dx row stride (floats): 68%32=4 spreads rows
constexpr int BWSZ = C_ * BSTR;   // 544 floats per wave

// Recurrence on halved increments (DA=da/2, DB=db/2), true-scale outputs.
#define RSTEP(DA, DB, CFV)                                    \
  do {                                                        \
    const float w_ = __builtin_fmaf((DA), (2.f/3.f), s1a);    \
    const float z_ = __builtin_fmaf((DA), (4.f/3.f), s1a);    \
    (CFV) = __builtin_fmaf((DB), w_, S2);                     \
    S2  = __builtin_fmaf((DB), z_, (CFV));                    \
    s1a = __builtin_fmaf((DA), 2.f, s1a);                     \
  } while (0)

// Two channels' worth of uniform p reads + 16 fma into S3[K0], S3[K0+1].
#define S3PAIR(PS, K0)                                                  \
  do {                                                                  \
    const float4 qa = *(const float4*)((PS) + (K0) * L_);               \
    const float4 qb = *(const float4*)((PS) + (K0) * L_ + 4);           \
    const float4 qc = *(const float4*)((PS) + (K0 + 1) * L_);           \
    const float4 qd = *(const float4*)((PS) + (K0 + 1) * L_ + 4);       \
    S3[K0] = __builtin_fmaf(d0, qa.x, S3[K0]);                          \
    S3[K0] = __builtin_fmaf(d1, qa.y, S3[K0]);                          \
    S3[K0] = __builtin_fmaf(d2, qa.z, S3[K0]);                          \
    S3[K0] = __builtin_fmaf(d3, qa.w, S3[K0]);                          \
    S3[K0] = __builtin_fmaf(d4, qb.x, S3[K0]);                          \
    S3[K0] = __builtin_fmaf(d5, qb.y, S3[K0]);                          \
    S3[K0] = __builtin_fmaf(d6, qb.z, S3[K0]);                          \
    S3[K0] = __builtin_fmaf(d7, qb.w, S3[K0]);                          \
    S3[K0 + 1] = __builtin_fmaf(d0, qc.x, S3[K0 + 1]);                  \
    S3[K0 + 1] = __builtin_fmaf(d1, qc.y, S3[K0 + 1]);                  \
    S3[K0 + 1] = __builtin_fmaf(d2, qc.z, S3[K0 + 1]);                  \
    S3[K0 + 1] = __builtin_fmaf(d3, qc.w, S3[K0 + 1]);                  \
    S3[K0 + 1] = __builtin_fmaf(d4, qd.x, S3[K0 + 1]);                  \
    S3[K0 + 1] = __builtin_fmaf(d5, qd.y, S3[K0 + 1]);                  \
    S3[K0 + 1] = __builtin_fmaf(d6, qd.z, S3[K0 + 1]);                  \
    S3[K0 + 1] = __builtin_fmaf(d7, qd.w, S3[K0 + 1]);                  \
  } while (0)

__global__ __launch_bounds__(256, 6)
void sig_chunks_kernel(const float* __restrict__ path, float* __restrict__ csig,
                       int G, int CPC) {
  __shared__ __align__(16) float Bs[4][BWSZ];   // 8.7 KB
  const int wid  = __builtin_amdgcn_readfirstlane((int)(threadIdx.x >> 6));
  const int lane = (int)(threadIdx.x & 63);
  const int ia = lane >> 3;   // 'a' == staging channel
  const int ib = lane & 7;    // 'b' == staging position
  const int wglob = __builtin_amdgcn_readfirstlane((int)blockIdx.x) * 4 + wid;
  const int samp = wglob / G;
  const int g    = wglob - samp * G;
  const int ts = g * CPC;
  const int te = (ts + CPC < NINC) ? (ts + CPC) : NINC;   // exclusive end
  const float* pbase = path + (size_t)samp * (C_ * L_);   // uniform per wave
  float* bs = Bs[wid];

  const int si = ib;
  const float* prow = pbase + ia * L_;     // per-lane staging row
  const int grp = lane & ~7;
  const float* pa = bs + ia * BSTR;
  const float* pb = bs + ib * BSTR;

  float S3[8];
#pragma unroll
  for (int k = 0; k < 8; ++k) S3[k] = 0.f;
  float S2 = 0.f, s1a = 0.f, cfp = 0.f;

  const int ntiles = (CPC + TILE - 1) / TILE;   // uniform across grid

  // prologue: prefetch tile 0 + boundary into regs
  float4 r0 = *(const float4*)(prow + ts + si * 4);
  float4 r1 = *(const float4*)(prow + ts + 32 + si * 4);
  float bnd = prow[ts + TILE];

  for (int tt = 0; tt < ntiles; ++tt) {
    const int t0 = ts + tt * TILE;
    const int cnt_ = te - t0;
    const int cnt = (cnt_ < TILE) ? cnt_ : TILE;

    // ---- stage tile tt: halved diffs into [c][t] LDS ----
    {
      const float4 v0 = r0, v1 = r1;
      const float sA = __shfl(v0.x, lane + 1);
      const float sB = __shfl(v1.x, grp);
      const float sC = __shfl(v1.x, lane + 1);
      const float n0 = (si == 7) ? sB : sA;
      const float n1 = (si == 7) ? bnd : sC;
      float4 e0, e1;
      e0.x = (v0.y - v0.x) * 0.5f;
      e0.y = (v0.z - v0.y) * 0.5f;
      e0.z = (v0.w - v0.z) * 0.5f;
      e0.w = (n0 - v0.w) * 0.5f;
      e1.x = (v1.y - v1.x) * 0.5f;
      e1.y = (v1.z - v1.y) * 0.5f;
      e1.z = (v1.w - v1.z) * 0.5f;
      e1.w = (n1 - v1.w) * 0.5f;
      *(float4*)(bs + ia * BSTR + si * 4) = e0;
      *(float4*)(bs + ia * BSTR + 32 + si * 4) = e1;
    }

    // ---- prefetch tile tt+1 into regs ----
    if (tt + 1 < ntiles) {
      const int t1g = t0 + TILE;
      r0 = *(const float4*)(prow + t1g + si * 4);
      r1 = *(const float4*)(prow + t1g + 32 + si * 4);
      const int bn = t1g + TILE;
      bnd = (bn < L_) ? prow[bn] : 0.f;
    }

    if (cnt == TILE) {
#pragma unroll
      for (int blk = 0; blk < 8; ++blk) {
        const int u0 = blk * 8;
        const float4 a0 = *(const float4*)(pa + u0);
        const float4 a1 = *(const float4*)(pa + u0 + 4);
        const float4 b0 = *(const float4*)(pb + u0);
        const float4 b1 = *(const float4*)(pb + u0 + 4);
        float c0, c1, c2, c3, c4, c5, c6, c7;
        RSTEP(a0.x, b0.x, c0);
        RSTEP(a0.y, b0.y, c1);
        RSTEP(a0.z, b0.z, c2);
        RSTEP(a0.w, b0.w, c3);
        RSTEP(a1.x, b1.x, c4);
        RSTEP(a1.y, b1.y, c5);
        RSTEP(a1.z, b1.z, c6);
        RSTEP(a1.w, b1.w, c7);
        const float d0 = cfp - c0, d1 = c0 - c1, d2 = c1 - c2, d3 = c2 - c3;
        const float d4 = c3 - c4, d5 = c4 - c5, d6 = c5 - c6, d7 = c6 - c7;
        cfp = c7;
        const float* ps = pbase + t0 + u0;   // identical in all lanes
        S3PAIR(ps, 0);
        S3PAIR(ps, 2);
        S3PAIR(ps, 4);
        S3PAIR(ps, 6);
      }
    } else {
      // tail tile (only the last chunk's last tile, cnt=63): cold path.
      // All p loads stay in-bounds; pad with d=0 for u>=m.
      for (int blk = 0; blk < 8; ++blk) {
        const int u0 = blk * 8;
        int m = cnt - u0; if (m > 8) m = 8;
        if (m <= 0) break;
        const float4 a0 = *(const float4*)(pa + u0);
        const float4 a1 = *(const float4*)(pa + u0 + 4);
        const float4 b0 = *(const float4*)(pb + u0);
        const float4 b1 = *(const float4*)(pb + u0 + 4);
        const float da[8] = {a0.x, a0.y, a0.z, a0.w, a1.x, a1.y, a1.z, a1.w};
        const float db[8] = {b0.x, b0.y, b0.z, b0.w, b1.x, b1.y, b1.z, b1.w};
        float dv[8];
#pragma unroll
        for (int u = 0; u < 8; ++u) {
          if (u < m) {
            float cf;
            RSTEP(da[u], db[u], cf);
            dv[u] = cfp - cf;
            cfp = cf;
          } else {
            dv[u] = 0.f;
          }
        }
        const float d0 = dv[0], d1 = dv[1], d2 = dv[2], d3 = dv[3];
        const float d4 = dv[4], d5 = dv[5], d6 = dv[6], d7 = dv[7];
        const float* ps = pbase + t0 + u0;
        S3PAIR(ps, 0);
        S3PAIR(ps, 2);
        S3PAIR(ps, 4);
        S3PAIR(ps, 6);
      }
    }
  }

  // Abel boundary: S3[k] += cfp * p[k][te]  (te <= 8191, in-bounds)
  float S3f[8];
  const float* pe = pbase + te;
#pragma unroll
  for (int k = 0; k < 8; ++k)
    S3f[k] = __builtin_fmaf(cfp, pe[k * L_], S3[k]);

  float* cs = csig + ((size_t)samp * G + g) * SIGDIM;
  if (ib == 0) cs[ia] = s1a;
  cs[8 + lane] = S2;
  float4 o0, o1;
  o0.x = S3f[0]; o0.y = S3f[1]; o0.z = S3f[2]; o0.w = S3f[3];
  o1.x = S3f[4]; o1.y = S3f[5]; o1.z = S3f[6]; o1.w = S3f[7];
  *(float4*)(cs + 72 + lane * 8)     = o0;
  *(float4*)(cs + 72 + lane * 8 + 4) = o1;
}

__global__ __launch_bounds__(256)
void sig_combine_kernel(const float* __restrict__ csig, float* __restrict__ out, int G) {
  const int wid  = __builtin_amdgcn_readfirstlane((int)(threadIdx.x >> 6));
  const int lane = (int)(threadIdx.x & 63);
  const int ia = lane >> 3, ib = lane & 7;
  const int samp = __builtin_amdgcn_readfirstlane((int)blockIdx.x) * 4 + wid;
  const float* base = csig + (size_t)samp * G * SIGDIM;

  float R1a = base[ia];
  float R2  = base[8 + lane];
  float R3[8];
#pragma unroll
  for (int k = 0; k < 8; ++k) R3[k] = base[72 + lane * 8 + k];

  for (int g = 1; g < G; ++g) {
    const float* T = base + g * SIGDIM;
    float sT1[8];
#pragma unroll
    for (int k = 0; k < 8; ++k) sT1[k] = T[k];
    const float T1a  = T[ia];
    const float T1b  = T[ib];
    const float T2ab = T[8 + lane];
    float T2b[8], T3v[8];
#pragma unroll
    for (int k = 0; k < 8; ++k) T2b[k] = T[8 + ib * 8 + k];
#pragma unroll
    for (int k = 0; k < 8; ++k) T3v[k] = T[72 + lane * 8 + k];
    const float R1o = R1a, R2o = R2;
#pragma unroll
    for (int k = 0; k < 8; ++k)
      R3[k] += T3v[k] + R1o * T2b[k] + R2o * sT1[k];
    R2  += T2ab + R1o * T1b;
    R1a += T1a;
  }

  float* o = out + (size_t)samp * SIGDIM;
  if (ib == 0) o[ia] = R1a;
  o[8 + lane] = R2;
#pragma unroll
  for (int k = 0; k < 8; ++k) o[72 + lane * 8 + k] = R3[k];
}

extern "C" void kernel_launch(void* const* d_in, const int* in_sizes, int n_in,
                              void* d_out, int out_size, void* d_ws, size_t ws_size,
                              hipStream_t stream) {
  (void)in_sizes; (void)n_in; (void)out_size;
  const float* path = (const float*)d_in[0];
  float* out = (float*)d_out;
  float* ws  = (float*)d_ws;

  int G = 16;
  while (G > 1 && (size_t)B_ * G * SIGDIM * sizeof(float) > ws_size) G >>= 1;
  const int CPC = (NINC + G - 1) / G;   // increments per chunk

  sig_chunks_kernel<<<dim3(B_ * G / 4), dim3(256), 0, stream>>>(path, ws, G, CPC);
  sig_combine_kernel<<<dim3(B_ / 4), dim3(256), 0, stream>>>(ws, out, G);
}

// Round 8
// 200.562 us; speedup vs baseline: 1.6379x; 1.2205x over previous
//
#include <hip/hip_runtime.h>

// Truncated signature, depth=3, C=8, B=512, L=8192.
// Kernel 1: one wave per (sample, chunk); sequential Chen steps over the chunk.
//   lane (a,b)=(lane>>3, lane&7) owns S2[a][b], S3[a][b][0..7].
//   Level-3 via Abel summation over the chunk:
//     S3[k] = sum_v (cf_{v-1}-cf_v) * p[k][v] + cf_last * p[k][te],  cf_{ts-1}=0
//   cf = true level-2 coefficient (S2 + S1*db/2 + da*db/6).
//   p[k][v] is wave-uniform raw path -> VMEM float4 loads, software-pipelined
//   one half-block (4 steps) ahead into named register sets qa/qb so L2 latency
//   hides under the previous half-block's VALU work.
//   LDS holds ONLY dx/2 in [c][t] layout (stride 68), per-wave private, no
//   barriers; per-lane da/db come from 2x ds_read_b128 per half-block.
// Kernel 2: per-sample in-order Chen combine of the G chunk signatures.

typedef float f2 __attribute__((ext_vector_type(2)));

constexpr int B_ = 512;
constexpr int C_ = 8;
constexpr int L_ = 8192;
constexpr int NINC = L_ - 1;      // 8191 increments
constexpr int SIGDIM = 584;       // 8 + 64 + 512
constexpr int TILE = 64;          // steps per LDS tile
constexpr int BSTR = 68;          // dx row stride (floats): 68%32=4 spreads rows
constexpr int BWSZ = C_ * BSTR;   // 544 floats per wave
constexpr int TGMAX = 8188;       // clamp for issue index: TG+3 <= 8191

// Recurrence on halved increments (DA=da/2, DB=db/2), true-scale outputs.
#define RSTEP(DA, DB, CFV)                                    \
  do {                                                        \
    const float w_ = __builtin_fmaf((DA), (2.f/3.f), s1a);    \
    const float z_ = __builtin_fmaf((DA), (4.f/3.f), s1a);    \
    (CFV) = __builtin_fmaf((DB), w_, S2);                     \
    S2  = __builtin_fmaf((DB), z_, (CFV));                    \
    s1a = __builtin_fmaf((DA), 2.f, s1a);                     \
  } while (0)

// Load 8 channels x 4 steps of raw path at uniform index TG into QP0..QP7.
#define ISSUE(QP, TG)                                         \
  do {                                                        \
    const float* ps_ = pbase + (TG);                          \
    QP##0 = *(const float4*)(ps_);                            \
    QP##1 = *(const float4*)(ps_ + L_);                       \
    QP##2 = *(const float4*)(ps_ + 2 * L_);                   \
    QP##3 = *(const float4*)(ps_ + 3 * L_);                   \
    QP##4 = *(const float4*)(ps_ + 4 * L_);                   \
    QP##5 = *(const float4*)(ps_ + 5 * L_);                   \
    QP##6 = *(const float4*)(ps_ + 6 * L_);                   \
    QP##7 = *(const float4*)(ps_ + 7 * L_);                   \
  } while (0)

#define S3HB(QP, K, DP0, DP1)                                                   \
  do {                                                                          \
    S3p[K] = __builtin_elementwise_fma(DP0, f2{QP##K.x, QP##K.y}, S3p[K]);      \
    S3p[K] = __builtin_elementwise_fma(DP1, f2{QP##K.z, QP##K.w}, S3p[K]);      \
  } while (0)

// One half-block (4 steps at local offset U0LOC) consuming register set QP.
#define COMPUTE(QP, U0LOC)                                    \
  do {                                                        \
    const float4 av = *(const float4*)(pa + (U0LOC));         \
    const float4 bv = *(const float4*)(pb + (U0LOC));         \
    float c0, c1, c2, c3;                                     \
    RSTEP(av.x, bv.x, c0);                                    \
    RSTEP(av.y, bv.y, c1);                                    \
    RSTEP(av.z, bv.z, c2);                                    \
    RSTEP(av.w, bv.w, c3);                                    \
    f2 dp0, dp1;                                              \
    dp0.x = cfp - c0; dp0.y = c0 - c1;                        \
    dp1.x = c1 - c2;  dp1.y = c2 - c3;                        \
    cfp = c3;                                                 \
    S3HB(QP, 0, dp0, dp1);                                    \
    S3HB(QP, 1, dp0, dp1);                                    \
    S3HB(QP, 2, dp0, dp1);                                    \
    S3HB(QP, 3, dp0, dp1);                                    \
    S3HB(QP, 4, dp0, dp1);                                    \
    S3HB(QP, 5, dp0, dp1);                                    \
    S3HB(QP, 6, dp0, dp1);                                    \
    S3HB(QP, 7, dp0, dp1);                                    \
  } while (0)

__global__ __launch_bounds__(256, 4)
void sig_chunks_kernel(const float* __restrict__ path, float* __restrict__ csig,
                       int G, int CPC) {
  __shared__ __align__(16) float Bs[4][BWSZ];   // 8.7 KB
  const int wid  = __builtin_amdgcn_readfirstlane((int)(threadIdx.x >> 6));
  const int lane = (int)(threadIdx.x & 63);
  const int ia = lane >> 3;   // 'a' == staging channel
  const int ib = lane & 7;    // 'b' == staging position
  const int wglob = __builtin_amdgcn_readfirstlane((int)blockIdx.x) * 4 + wid;
  const int samp = wglob / G;
  const int g    = wglob - samp * G;
  const int ts = g * CPC;
  const int te = (ts + CPC < NINC) ? (ts + CPC) : NINC;   // exclusive end
  const float* pbase = path + (size_t)samp * (C_ * L_);   // uniform per wave
  float* bs = Bs[wid];

  const int si = ib;
  const float* prow = pbase + ia * L_;     // per-lane staging row
  const int grp = lane & ~7;
  const float* pa = bs + ia * BSTR;
  const float* pb = bs + ib * BSTR;

  f2 S3p[8];
#pragma unroll
  for (int k = 0; k < 8; ++k) S3p[k] = f2{0.f, 0.f};
  float S2 = 0.f, s1a = 0.f, cfp = 0.f;

  const int ntiles = (CPC + TILE - 1) / TILE;   // uniform across grid

  // prologue: prefetch staging tile 0 + boundary, and pipeline-prime qa
  float4 r0 = *(const float4*)(prow + ts + si * 4);
  float4 r1 = *(const float4*)(prow + ts + 32 + si * 4);
  float bnd = prow[ts + TILE];
  float4 qa0, qa1, qa2, qa3, qa4, qa5, qa6, qa7;
  float4 qb0, qb1, qb2, qb3, qb4, qb5, qb6, qb7;
  ISSUE(qa, ts);

  for (int tt = 0; tt < ntiles; ++tt) {
    const int t0 = ts + tt * TILE;
    const int cnt_ = te - t0;
    const int cnt = (cnt_ < TILE) ? cnt_ : TILE;

    // ---- stage tile tt: halved diffs into [c][t] LDS ----
    {
      const float4 v0 = r0, v1 = r1;
      const float sA = __shfl(v0.x, lane + 1);
      const float sB = __shfl(v1.x, grp);
      const float sC = __shfl(v1.x, lane + 1);
      const float n0 = (si == 7) ? sB : sA;
      const float n1 = (si == 7) ? bnd : sC;
      float4 e0, e1;
      e0.x = (v0.y - v0.x) * 0.5f;
      e0.y = (v0.z - v0.y) * 0.5f;
      e0.z = (v0.w - v0.z) * 0.5f;
      e0.w = (n0 - v0.w) * 0.5f;
      e1.x = (v1.y - v1.x) * 0.5f;
      e1.y = (v1.z - v1.y) * 0.5f;
      e1.z = (v1.w - v1.z) * 0.5f;
      e1.w = (n1 - v1.w) * 0.5f;
      *(float4*)(bs + ia * BSTR + si * 4) = e0;
      *(float4*)(bs + ia * BSTR + 32 + si * 4) = e1;
    }

    // ---- prefetch staging for tile tt+1 ----
    if (tt + 1 < ntiles) {
      const int t1g = t0 + TILE;
      r0 = *(const float4*)(prow + t1g + si * 4);
      r1 = *(const float4*)(prow + t1g + 32 + si * 4);
      const int bn = t1g + TILE;
      bnd = (bn < L_) ? prow[bn] : 0.f;
    }

    if (cnt == TILE) {
      // 16 half-blocks, software-pipelined: issue next set, compute current.
      // qa enters holding data for t0 (carried from previous tile / prologue).
#pragma unroll
      for (int j = 0; j < 8; ++j) {
        int tg1 = t0 + j * 8 + 4;
        tg1 = (tg1 > TGMAX) ? TGMAX : tg1;
        ISSUE(qb, tg1);
        COMPUTE(qa, j * 8);
        int tg2 = t0 + j * 8 + 8;   // j=7: first half-block of next tile
        tg2 = (tg2 > TGMAX) ? TGMAX : tg2;
        ISSUE(qa, tg2);
        COMPUTE(qb, j * 8 + 4);
      }
    } else {
      // tail tile (only the last chunk's last tile, cnt=63): cold path.
      const int nfull = cnt >> 2;
      for (int h = 0; h < nfull; ++h) {
        ISSUE(qb, t0 + h * 4);
        COMPUTE(qb, h * 4);
      }
      for (int u = nfull * 4; u < cnt; ++u) {
        const float dav = pa[u];
        const float dbv = pb[u];
        float cf;
        RSTEP(dav, dbv, cf);
        const float dd = cfp - cf;
        cfp = cf;
        const float* ps_ = pbase + t0 + u;
#pragma unroll
        for (int k = 0; k < 8; ++k)
          S3p[k].x = __builtin_fmaf(dd, ps_[k * L_], S3p[k].x);
      }
    }
  }

  // Abel boundary + fold f2 halves: S3[k] = S3p.x + S3p.y + cfp * p[k][te]
  float S3f[8];
  const float* pe = pbase + te;   // te <= 8191, in-bounds
#pragma unroll
  for (int k = 0; k < 8; ++k)
    S3f[k] = S3p[k].x + S3p[k].y + cfp * pe[k * L_];

  float* cs = csig + ((size_t)samp * G + g) * SIGDIM;
  if (ib == 0) cs[ia] = s1a;
  cs[8 + lane] = S2;
  float4 o0, o1;
  o0.x = S3f[0]; o0.y = S3f[1]; o0.z = S3f[2]; o0.w = S3f[3];
  o1.x = S3f[4]; o1.y = S3f[5]; o1.z = S3f[6]; o1.w = S3f[7];
  *(float4*)(cs + 72 + lane * 8)     = o0;
  *(float4*)(cs + 72 + lane * 8 + 4) = o1;
}

__global__ __launch_bounds__(256)
void sig_combine_kernel(const float* __restrict__ csig, float* __restrict__ out, int G) {
  const int wid  = __builtin_amdgcn_readfirstlane((int)(threadIdx.x >> 6));
  const int lane = (int)(threadIdx.x & 63);
  const int ia = lane >> 3, ib = lane & 7;
  const int samp = __builtin_amdgcn_readfirstlane((int)blockIdx.x) * 4 + wid;
  const float* base = csig + (size_t)samp * G * SIGDIM;

  float R1a = base[ia];
  float R2  = base[8 + lane];
  float R3[8];
#pragma unroll
  for (int k = 0; k < 8; ++k) R3[k] = base[72 + lane * 8 + k];

  for (int g = 1; g < G; ++g) {
    const float* T = base + g * SIGDIM;
    float sT1[8];
#pragma unroll
    for (int k = 0; k < 8; ++k) sT1[k] = T[k];
    const float T1a  = T[ia];
    const float T1b  = T[ib];
    const float T2ab = T[8 + lane];
    float T2b[8], T3v[8];
#pragma unroll
    for (int k = 0; k < 8; ++k) T2b[k] = T[8 + ib * 8 + k];
#pragma unroll
    for (int k = 0; k < 8; ++k) T3v[k] = T[72 + lane * 8 + k];
    const float R1o = R1a, R2o = R2;
#pragma unroll
    for (int k = 0; k < 8; ++k)
      R3[k] += T3v[k] + R1o * T2b[k] + R2o * sT1[k];
    R2  += T2ab + R1o * T1b;
    R1a += T1a;
  }

  float* o = out + (size_t)samp * SIGDIM;
  if (ib == 0) o[ia] = R1a;
  o[8 + lane] = R2;
#pragma unroll
  for (int k = 0; k < 8; ++k) o[72 + lane * 8 + k] = R3[k];
}

extern "C" void kernel_launch(void* const* d_in, const int* in_sizes, int n_in,
                              void* d_out, int out_size, void* d_ws, size_t ws_size,
                              hipStream_t stream) {
  (void)in_sizes; (void)n_in; (void)out_size;
  const float* path = (const float*)d_in[0];
  float* out = (float*)d_out;
  float* ws  = (float*)d_ws;

  int G = 16;
  while (G > 1 && (size_t)B_ * G * SIGDIM * sizeof(float) > ws_size) G >>= 1;
  const int CPC = (NINC + G - 1) / G;   // increments per chunk

  sig_chunks_kernel<<<dim3(B_ * G / 4), dim3(256), 0, stream>>>(path, ws, G, CPC);
  sig_combine_kernel<<<dim3(B_ / 4), dim3(256), 0, stream>>>(ws, out, G);
}

// Round 9
// 146.641 us; speedup vs baseline: 2.2402x; 1.3677x over previous
//
#include <hip/hip_runtime.h>

// Truncated signature, depth=3, C=8, B=512, L=8192.
// Kernel 1: one wave per (sample, chunk); sequential Chen steps over the chunk.
//   lane (a,b)=(lane>>3, lane&7) owns S2[a][b], S3[a][b][0..7].
//   Direct form: S3[k] += cf * dx2[k][u], cf = S2 + S1*db/2 + da*db/6.
//   Broadcast operand dx2[k][u] comes from the STAGING REGISTERS via
//   v_readlane (compile-time lane k*8+(u>>2)) -> SGPR operand of v_fmac.
//   Zero DS traffic for the broadcast. LDS holds dx/2 in [c][t] (stride 68)
//   only for the per-lane da/db octet reads (4x ds_read_b128 per 8 steps).
//   Per-wave private LDS slice, no barriers.
// Kernel 2: per-sample in-order Chen combine of the G chunk signatures.

constexpr int B_ = 512;
constexpr int C_ = 8;
constexpr int L_ = 8192;
constexpr int NINC = L_ - 1;      // 8191 increments
constexpr int SIGDIM = 584;       // 8 + 64 + 512
constexpr int TILE = 64;          // steps per LDS tile
constexpr int BSTR = 68;          // dx row stride (floats): 68%32=4 spreads rows
constexpr int BWSZ = C_ * BSTR;   // 544 floats per wave

static __device__ __forceinline__ float rl(float v, int l) {
  return __int_as_float(__builtin_amdgcn_readlane(__float_as_int(v), l));
}

// Recurrence on halved increments (DA=da/2, DB=db/2), true-scale cf/S2/S1.
#define RSTEP(DA, DB, CFV)                                    \
  do {                                                        \
    const float w_ = __builtin_fmaf((DA), (2.f/3.f), s1a);    \
    const float z_ = __builtin_fmaf((DA), (4.f/3.f), s1a);    \
    (CFV) = __builtin_fmaf((DB), w_, S2);                     \
    S2  = __builtin_fmaf((DB), z_, (CFV));                    \
    s1a = __builtin_fmaf((DA), 2.f, s1a);                     \
  } while (0)

// One step's S3 update: broadcast EC (one diff component) from lanes k*8+Q.
#define S3ROW(EC, Q, CF)                                      \
  do {                                                        \
    S3[0] = __builtin_fmaf((CF), rl((EC), 0 + (Q)), S3[0]);   \
    S3[1] = __builtin_fmaf((CF), rl((EC), 8 + (Q)), S3[1]);   \
    S3[2] = __builtin_fmaf((CF), rl((EC), 16 + (Q)), S3[2]);  \
    S3[3] = __builtin_fmaf((CF), rl((EC), 24 + (Q)), S3[3]);  \
    S3[4] = __builtin_fmaf((CF), rl((EC), 32 + (Q)), S3[4]);  \
    S3[5] = __builtin_fmaf((CF), rl((EC), 40 + (Q)), S3[5]);  \
    S3[6] = __builtin_fmaf((CF), rl((EC), 48 + (Q)), S3[6]);  \
    S3[7] = __builtin_fmaf((CF), rl((EC), 56 + (Q)), S3[7]);  \
  } while (0)

// Half-block: 4 steps; E = diff reg (float4), Q = si quad, AV/BV = da/db.
#define HB(E, Q, AV, BV)                                      \
  do {                                                        \
    float cf_;                                                \
    RSTEP((AV).x, (BV).x, cf_); S3ROW((E).x, (Q), cf_);       \
    RSTEP((AV).y, (BV).y, cf_); S3ROW((E).y, (Q), cf_);       \
    RSTEP((AV).z, (BV).z, cf_); S3ROW((E).z, (Q), cf_);       \
    RSTEP((AV).w, (BV).w, cf_); S3ROW((E).w, (Q), cf_);       \
  } while (0)

__global__ __launch_bounds__(256, 6)
void sig_chunks_kernel(const float* __restrict__ path, float* __restrict__ csig,
                       int G, int CPC) {
  __shared__ __align__(16) float Bs[4][BWSZ];   // 8.7 KB
  const int wid  = __builtin_amdgcn_readfirstlane((int)(threadIdx.x >> 6));
  const int lane = (int)(threadIdx.x & 63);
  const int ia = lane >> 3;   // 'a' == staging channel
  const int ib = lane & 7;    // 'b' == staging position
  const int wglob = __builtin_amdgcn_readfirstlane((int)blockIdx.x) * 4 + wid;
  const int samp = wglob / G;
  const int g    = wglob - samp * G;
  const int ts = g * CPC;
  const int te = (ts + CPC < NINC) ? (ts + CPC) : NINC;   // exclusive end
  const float* pbase = path + (size_t)samp * (C_ * L_);
  float* bs = Bs[wid];

  const int si = ib;
  const float* prow = pbase + ia * L_;     // per-lane staging row
  const int grp = lane & ~7;
  const float* pa = bs + ia * BSTR;
  const float* pb = bs + ib * BSTR;

  float S3[8];
#pragma unroll
  for (int k = 0; k < 8; ++k) S3[k] = 0.f;
  float S2 = 0.f, s1a = 0.f;

  const int ntiles = (CPC + TILE - 1) / TILE;   // uniform across grid

  // prologue: prefetch tile 0 + boundary into regs
  float4 r0 = *(const float4*)(prow + ts + si * 4);
  float4 r1 = *(const float4*)(prow + ts + 32 + si * 4);
  float bnd = prow[ts + TILE];
  float4 e0t, e1t;   // current tile's halved diffs (this lane's 8 slots)

  for (int tt = 0; tt < ntiles; ++tt) {
    const int t0 = ts + tt * TILE;
    const int cnt_ = te - t0;
    const int cnt = (cnt_ < TILE) ? cnt_ : TILE;

    // ---- stage tile tt: halved diffs -> regs (kept!) + [c][t] LDS ----
    {
      const float4 v0 = r0, v1 = r1;
      const float sA = __shfl(v0.x, lane + 1);
      const float sB = __shfl(v1.x, grp);
      const float sC = __shfl(v1.x, lane + 1);
      const float n0 = (si == 7) ? sB : sA;
      const float n1 = (si == 7) ? bnd : sC;
      e0t.x = (v0.y - v0.x) * 0.5f;
      e0t.y = (v0.z - v0.y) * 0.5f;
      e0t.z = (v0.w - v0.z) * 0.5f;
      e0t.w = (n0 - v0.w) * 0.5f;
      e1t.x = (v1.y - v1.x) * 0.5f;
      e1t.y = (v1.z - v1.y) * 0.5f;
      e1t.z = (v1.w - v1.z) * 0.5f;
      e1t.w = (n1 - v1.w) * 0.5f;
      *(float4*)(bs + ia * BSTR + si * 4) = e0t;
      *(float4*)(bs + ia * BSTR + 32 + si * 4) = e1t;
    }

    // ---- prefetch tile tt+1 into regs ----
    if (tt + 1 < ntiles) {
      const int t1g = t0 + TILE;
      r0 = *(const float4*)(prow + t1g + si * 4);
      r1 = *(const float4*)(prow + t1g + 32 + si * 4);
      const int bn = t1g + TILE;
      bnd = (bn < L_) ? prow[bn] : 0.f;
    }

    if (cnt == TILE) {
#pragma unroll
      for (int blk = 0; blk < 8; ++blk) {
        const int u0 = blk * 8;
        const float4 a0 = *(const float4*)(pa + u0);
        const float4 a1 = *(const float4*)(pa + u0 + 4);
        const float4 b0 = *(const float4*)(pb + u0);
        const float4 b1 = *(const float4*)(pb + u0 + 4);
        const float4 E = (blk < 4) ? e0t : e1t;   // resolved after unroll
        const int q0 = (blk & 3) * 2;
        HB(E, q0, a0, b0);
        HB(E, q0 + 1, a1, b1);
      }
    } else {
      // tail tile (last chunk only, cnt=63): uniform LDS b32 broadcast.
      for (int u = 0; u < cnt; ++u) {
        const float dav = pa[u];
        const float dbv = pb[u];
        float cf;
        RSTEP(dav, dbv, cf);
#pragma unroll
        for (int k = 0; k < 8; ++k)
          S3[k] = __builtin_fmaf(cf, bs[k * BSTR + u], S3[k]);
      }
    }
  }

  float* cs = csig + ((size_t)samp * G + g) * SIGDIM;
  if (ib == 0) cs[ia] = s1a;
  cs[8 + lane] = S2;
  float4 o0, o1;
  o0.x = 2.f * S3[0]; o0.y = 2.f * S3[1]; o0.z = 2.f * S3[2]; o0.w = 2.f * S3[3];
  o1.x = 2.f * S3[4]; o1.y = 2.f * S3[5]; o1.z = 2.f * S3[6]; o1.w = 2.f * S3[7];
  *(float4*)(cs + 72 + lane * 8)     = o0;
  *(float4*)(cs + 72 + lane * 8 + 4) = o1;
}

__global__ __launch_bounds__(256)
void sig_combine_kernel(const float* __restrict__ csig, float* __restrict__ out, int G) {
  const int wid  = __builtin_amdgcn_readfirstlane((int)(threadIdx.x >> 6));
  const int lane = (int)(threadIdx.x & 63);
  const int ia = lane >> 3, ib = lane & 7;
  const int samp = __builtin_amdgcn_readfirstlane((int)blockIdx.x) * 4 + wid;
  const float* base = csig + (size_t)samp * G * SIGDIM;

  float R1a = base[ia];
  float R2  = base[8 + lane];
  float R3[8];
#pragma unroll
  for (int k = 0; k < 8; ++k) R3[k] = base[72 + lane * 8 + k];

  for (int g = 1; g < G; ++g) {
    const float* T = base + g * SIGDIM;
    float sT1[8];
#pragma unroll
    for (int k = 0; k < 8; ++k) sT1[k] = T[k];
    const float T1a  = T[ia];
    const float T1b  = T[ib];
    const float T2ab = T[8 + lane];
    float T2b[8], T3v[8];
#pragma unroll
    for (int k = 0; k < 8; ++k) T2b[k] = T[8 + ib * 8 + k];
#pragma unroll
    for (int k = 0; k < 8; ++k) T3v[k] = T[72 + lane * 8 + k];
    const float R1o = R1a, R2o = R2;
#pragma unroll
    for (int k = 0; k < 8; ++k)
      R3[k] += T3v[k] + R1o * T2b[k] + R2o * sT1[k];
    R2  += T2ab + R1o * T1b;
    R1a += T1a;
  }

  float* o = out + (size_t)samp * SIGDIM;
  if (ib == 0) o[ia] = R1a;
  o[8 + lane] = R2;
#pragma unroll
  for (int k = 0; k < 8; ++k) o[72 + lane * 8 + k] = R3[k];
}

extern "C" void kernel_launch(void* const* d_in, const int* in_sizes, int n_in,
                              void* d_out, int out_size, void* d_ws, size_t ws_size,
                              hipStream_t stream) {
  (void)in_sizes; (void)n_in; (void)out_size;
  const float* path = (const float*)d_in[0];
  float* out = (float*)d_out;
  float* ws  = (float*)d_ws;

  int G = 16;
  while (G > 1 && (size_t)B_ * G * SIGDIM * sizeof(float) > ws_size) G >>= 1;
  const int CPC = (NINC + G - 1) / G;   // increments per chunk

  sig_chunks_kernel<<<dim3(B_ * G / 4), dim3(256), 0, stream>>>(path, ws, G, CPC);
  sig_combine_kernel<<<dim3(B_ / 4), dim3(256), 0, stream>>>(ws, out, G);
}